// Round 1
// baseline (662.518 us; speedup 1.0000x reference)
//
#include <hip/hip_runtime.h>
#include <hip/hip_bf16.h>

// LIF-with-refractory + per-neuron delay-line gather.
// N = B*C*H*W elements; buffer is [T_BUF, N]; output is [5, N]:
//   out[0] = z_delayed, out[1] = z, out[2] = v_new, out[3] = i_dec, out[4] = rho_new
//
// Constants (DT=1e-3): DT*TAU_MEM_INV=0.1, DT*TAU_SYN_INV=0.2, DT*TAU_REFRAC_INV=1.0
// V_TH=1, V_LEAK=0, V_RESET=0, RHO_RESET=5.

__global__ __launch_bounds__(256) void lif_step_kernel(
    const float4* __restrict__ i_new4,
    const float4* __restrict__ v4,
    const float4* __restrict__ i4,
    const float4* __restrict__ rho4,
    const float*  __restrict__ buffer,   // [T_BUF, N]
    const int4*   __restrict__ delay4,   // [N/4]
    float* __restrict__ out,             // [5, N]
    int n4, int N)
{
    // Exact-match float32 arithmetic vs numpy: no fma contraction (a contracted
    // v_dec could flip the z = (v_dec > 1.0f) comparison by 1 ulp).
    #pragma clang fp contract(off)

    int idx = blockIdx.x * blockDim.x + threadIdx.x;
    if (idx >= n4) return;

    float4 vin   = v4[idx];
    float4 iin   = i4[idx];
    float4 rin   = rho4[idx];
    float4 inewv = i_new4[idx];
    int4   dl    = delay4[idx];

    int n0 = idx << 2;

    float z[4], vnew[4], idec[4], rnew[4], zdel[4];

    const float vv[4] = {vin.x, vin.y, vin.z, vin.w};
    const float ii[4] = {iin.x, iin.y, iin.z, iin.w};
    const float rr[4] = {rin.x, rin.y, rin.z, rin.w};
    const float nn[4] = {inewv.x, inewv.y, inewv.z, inewv.w};
    const int   dd[4] = {dl.x, dl.y, dl.z, dl.w};

    #pragma unroll
    for (int j = 0; j < 4; ++j) {
        float refrac = (rr[j] > 0.0f) ? 1.0f : 0.0f;
        // v_dec = v + 0.1 * (1-refrac) * ((v_leak - v) + i)
        float v_dec = vv[j] + 0.1f * ((1.0f - refrac) * ((0.0f - vv[j]) + ii[j]));
        float zz = (v_dec > 1.0f) ? 1.0f : 0.0f;
        z[j]    = zz;
        vnew[j] = (1.0f - zz) * v_dec;            // + zz * V_RESET(=0)
        idec[j] = (ii[j] - 0.2f * ii[j]) + nn[j];
        rnew[j] = (rr[j] - refrac) + zz * 5.0f;   // DT*TAU_REFRAC_INV = 1.0 exactly
        // delay-line gather: buffer_new = [z, buffer[:-1]]
        int d = dd[j];
        if (d == 0) {
            zdel[j] = zz;
        } else {
            zdel[j] = buffer[(size_t)(d - 1) * (size_t)N + (size_t)(n0 + j)];
        }
    }

    ((float4*)(out + 0 * (size_t)N))[idx] = make_float4(zdel[0], zdel[1], zdel[2], zdel[3]);
    ((float4*)(out + 1 * (size_t)N))[idx] = make_float4(z[0],    z[1],    z[2],    z[3]);
    ((float4*)(out + 2 * (size_t)N))[idx] = make_float4(vnew[0], vnew[1], vnew[2], vnew[3]);
    ((float4*)(out + 3 * (size_t)N))[idx] = make_float4(idec[0], idec[1], idec[2], idec[3]);
    ((float4*)(out + 4 * (size_t)N))[idx] = make_float4(rnew[0], rnew[1], rnew[2], rnew[3]);
}

extern "C" void kernel_launch(void* const* d_in, const int* in_sizes, int n_in,
                              void* d_out, int out_size, void* d_ws, size_t ws_size,
                              hipStream_t stream) {
    const float* i_new  = (const float*)d_in[0];
    const float* v      = (const float*)d_in[1];
    const float* i_cur  = (const float*)d_in[2];
    const float* rho    = (const float*)d_in[3];
    const float* buffer = (const float*)d_in[4];
    const int*   delay  = (const int*)d_in[5];
    float* out = (float*)d_out;

    int N  = in_sizes[0];          // B*C*H*W
    int n4 = N >> 2;               // N divisible by 4 (W=64)

    int block = 256;
    int grid  = (n4 + block - 1) / block;

    lif_step_kernel<<<grid, block, 0, stream>>>(
        (const float4*)i_new, (const float4*)v, (const float4*)i_cur,
        (const float4*)rho, buffer, (const int4*)delay, out, n4, N);
}

// Round 2
// 658.740 us; speedup vs baseline: 1.0057x; 1.0057x over previous
//
#include <hip/hip_runtime.h>
#include <hip/hip_bf16.h>

// LIF-with-refractory + per-neuron delay-line gather.
// N = B*C*H*W; buffer is [T_BUF, N]; out is [5, N]:
//   out[0]=z_delayed, out[1]=z, out[2]=v_new, out[3]=i_dec, out[4]=rho_new
//
// R2: branchless gather (clamped row + select) so all 8 gather loads issue
// back-to-back with no exec-mask divergence; 8 elements/thread for MLP.
// Math expressions bit-identical to R1 (absmax was 0.0).

__global__ __launch_bounds__(256) void lif_step_kernel(
    const float4* __restrict__ i_new4,
    const float4* __restrict__ v4,
    const float4* __restrict__ i4,
    const float4* __restrict__ rho4,
    const float*  __restrict__ buffer,   // [T_BUF, N]
    const int4*   __restrict__ delay4,   // [N/4]
    float* __restrict__ out,             // [5, N]
    int n8, int N)
{
    // Exact-match float32 arithmetic vs numpy: no fma contraction.
    #pragma clang fp contract(off)

    int t = blockIdx.x * blockDim.x + threadIdx.x;
    if (t >= n8) return;

    int g  = t << 1;         // float4-group index (two groups per thread)
    int n0 = t << 3;         // first neuron index

    // ---- coalesced stream loads (dwordx4) ----
    float4 vinA = v4[g],     vinB = v4[g + 1];
    float4 iinA = i4[g],     iinB = i4[g + 1];
    float4 rinA = rho4[g],   rinB = rho4[g + 1];
    float4 nA   = i_new4[g], nB   = i_new4[g + 1];
    int4   dlA  = delay4[g], dlB  = delay4[g + 1];

    const float vv[8] = {vinA.x, vinA.y, vinA.z, vinA.w, vinB.x, vinB.y, vinB.z, vinB.w};
    const float ii[8] = {iinA.x, iinA.y, iinA.z, iinA.w, iinB.x, iinB.y, iinB.z, iinB.w};
    const float rr[8] = {rinA.x, rinA.y, rinA.z, rinA.w, rinB.x, rinB.y, rinB.z, rinB.w};
    const float nn[8] = {nA.x,   nA.y,   nA.z,   nA.w,   nB.x,   nB.y,   nB.z,   nB.w};
    const int   dd[8] = {dlA.x,  dlA.y,  dlA.z,  dlA.w,  dlB.x,  dlB.y,  dlB.z,  dlB.w};

    // ---- branchless delay-line gathers: issue all 8 loads up front ----
    // buffer_new = concat(z, buffer[:-1]) => d==0 -> z (selected later),
    // else buffer[(d-1)*N + n]. Clamp row so the load is always legal.
    float gbuf[8];
    #pragma unroll
    for (int j = 0; j < 8; ++j) {
        int d   = dd[j];
        int row = (d > 0) ? (d - 1) : 0;                 // clamp; selected out if d==0
        gbuf[j] = buffer[(size_t)((unsigned)row * (unsigned)N + (unsigned)(n0 + j))];
    }

    // ---- LIF pointwise math (overlaps gather latency) ----
    float z[8], vnew[8], idec[8], rnew[8], zdel[8];
    #pragma unroll
    for (int j = 0; j < 8; ++j) {
        float refrac = (rr[j] > 0.0f) ? 1.0f : 0.0f;
        float v_dec  = vv[j] + 0.1f * ((1.0f - refrac) * ((0.0f - vv[j]) + ii[j]));
        float zz     = (v_dec > 1.0f) ? 1.0f : 0.0f;
        z[j]    = zz;
        vnew[j] = (1.0f - zz) * v_dec;
        idec[j] = (ii[j] - 0.2f * ii[j]) + nn[j];
        rnew[j] = (rr[j] - refrac) + zz * 5.0f;          // DT*TAU_REFRAC_INV = 1.0
        zdel[j] = (dd[j] == 0) ? zz : gbuf[j];           // cndmask, no branch
    }

    // ---- coalesced stores (dwordx4 x2 per plane) ----
    float4* o0 = (float4*)(out + 0 * (size_t)N);
    float4* o1 = (float4*)(out + 1 * (size_t)N);
    float4* o2 = (float4*)(out + 2 * (size_t)N);
    float4* o3 = (float4*)(out + 3 * (size_t)N);
    float4* o4 = (float4*)(out + 4 * (size_t)N);

    o0[g]     = make_float4(zdel[0], zdel[1], zdel[2], zdel[3]);
    o0[g + 1] = make_float4(zdel[4], zdel[5], zdel[6], zdel[7]);
    o1[g]     = make_float4(z[0], z[1], z[2], z[3]);
    o1[g + 1] = make_float4(z[4], z[5], z[6], z[7]);
    o2[g]     = make_float4(vnew[0], vnew[1], vnew[2], vnew[3]);
    o2[g + 1] = make_float4(vnew[4], vnew[5], vnew[6], vnew[7]);
    o3[g]     = make_float4(idec[0], idec[1], idec[2], idec[3]);
    o3[g + 1] = make_float4(idec[4], idec[5], idec[6], idec[7]);
    o4[g]     = make_float4(rnew[0], rnew[1], rnew[2], rnew[3]);
    o4[g + 1] = make_float4(rnew[4], rnew[5], rnew[6], rnew[7]);
}

extern "C" void kernel_launch(void* const* d_in, const int* in_sizes, int n_in,
                              void* d_out, int out_size, void* d_ws, size_t ws_size,
                              hipStream_t stream) {
    const float* i_new  = (const float*)d_in[0];
    const float* v      = (const float*)d_in[1];
    const float* i_cur  = (const float*)d_in[2];
    const float* rho    = (const float*)d_in[3];
    const float* buffer = (const float*)d_in[4];
    const int*   delay  = (const int*)d_in[5];
    float* out = (float*)d_out;

    int N  = in_sizes[0];          // B*C*H*W (2^21 here)
    int n8 = N >> 3;               // N divisible by 8 (W=64)

    int block = 256;
    int grid  = (n8 + block - 1) / block;

    lif_step_kernel<<<grid, block, 0, stream>>>(
        (const float4*)i_new, (const float4*)v, (const float4*)i_cur,
        (const float4*)rho, buffer, (const int4*)delay, out, n8, N);
}